// Round 1
// baseline (1355.511 us; speedup 1.0000x reference)
//
#include <hip/hip_runtime.h>
#include <math.h>

#define NB  32
#define NS  4096
#define ND  2048
#define NDH 128
#define LUTN 4096

// Reference LUT semantics:
//   idx = mod(floor(theta * (4096 / 2pi)), 4096)          (floor-mod, f32 mult)
//   sin_tab[idx] = sin(idx * (2pi/4096))  (angle formed by f32 mult)
// We reproduce the quantization exactly and evaluate sin/cos of the quantized
// angle directly (identical to a table lookup up to ~1 ulp of sincosf).
static __device__ __forceinline__ void lut_sincos(float theta, float* s, float* c) {
    const float IDX_SCALE = (float)(4096.0 / (2.0 * 3.14159265358979323846));
    const float ANG_STEP  = (float)((2.0 * 3.14159265358979323846) / 4096.0);
    float f = floorf(theta * IDX_SCALE);
    int idx = ((int)f) & (LUTN - 1);   // & == floor-mod for pow2 on two's complement
    float ang = (float)idx * ANG_STEP;
    sincosf(ang, s, c);
}

// Pass 1: raw scores. One wave per 8 consecutive key rows (same b).
// lane holds dims d0 = 2*lane, 2*lane+1 of the 128-dim head.
__global__ __launch_bounds__(256) void scores_kernel(
    const float* __restrict__ x, const float* __restrict__ V,
    const float* __restrict__ t, const float* __restrict__ wq,
    const float* __restrict__ bq, const float* __restrict__ wk,
    const float* __restrict__ bk, float* __restrict__ scores)
{
    const int ROWS = 8;
    int lane  = threadIdx.x & 63;
    int gwave = blockIdx.x * 4 + (threadIdx.x >> 6);
    int row0  = gwave * ROWS;          // global row = b*NS + s
    int b  = row0 >> 12;               // NS = 4096
    int s0 = row0 & (NS - 1);
    int d0 = lane * 2;

    const float PHIF = (float)1.61803398874989484820458683436563811;
    float tphi = t[b] * PHIF;

    // query fragment for this lane's two dims (recomputed per wave, amortized over 8 rows)
    float qs0, qc0, qs1, qc1;
    {
        float xv0 = x[b * ND + d0];
        float xv1 = x[b * ND + d0 + 1];
        float th0 = (xv0 / (1.0f + fabsf(wq[d0]))     + bq[d0])     + tphi;
        float th1 = (xv1 / (1.0f + fabsf(wq[d0 + 1])) + bq[d0 + 1]) + tphi;
        lut_sincos(th0, &qs0, &qc0);
        lut_sincos(th1, &qs1, &qc1);
    }
    float den0 = 1.0f + fabsf(wk[d0]);
    float den1 = 1.0f + fabsf(wk[d0 + 1]);
    float bk0 = bk[d0], bk1 = bk[d0 + 1];

    const float* vp = V + ((size_t)(b * NS + s0)) * ND + d0;
    for (int r = 0; r < ROWS; ++r) {
        float2 kv = *(const float2*)(vp + (size_t)r * ND);
        float th0 = kv.x / den0 + bk0;
        float th1 = kv.y / den1 + bk1;
        float ks0, kc0, ks1, kc1;
        lut_sincos(th0, &ks0, &kc0);
        lut_sincos(th1, &ks1, &kc1);
        float acc = qc0 * kc0 + qs0 * ks0 + qc1 * kc1 + qs1 * ks1;
        #pragma unroll
        for (int off = 32; off > 0; off >>= 1)
            acc += __shfl_xor(acc, off, 64);
        if (lane == 0)
            scores[b * NS + s0 + r] = acc * 0.0625f;   // /16 == *2^-4, exact
    }
}

// Pass 2: in-place softmax over S per batch row. One block per b.
__global__ __launch_bounds__(256) void softmax_kernel(float* __restrict__ sw) {
    int b = blockIdx.x;
    float* p = sw + b * NS;
    int tid  = threadIdx.x;
    int lane = tid & 63, wid = tid >> 6;

    float vals[16];
    float m = -INFINITY;
    #pragma unroll
    for (int i = 0; i < 16; ++i) { vals[i] = p[tid + 256 * i]; m = fmaxf(m, vals[i]); }
    #pragma unroll
    for (int off = 32; off > 0; off >>= 1) m = fmaxf(m, __shfl_xor(m, off, 64));
    __shared__ float redm[4];
    if (lane == 0) redm[wid] = m;
    __syncthreads();
    m = fmaxf(fmaxf(redm[0], redm[1]), fmaxf(redm[2], redm[3]));

    float sum = 0.f;
    #pragma unroll
    for (int i = 0; i < 16; ++i) { vals[i] = expf(vals[i] - m); sum += vals[i]; }
    #pragma unroll
    for (int off = 32; off > 0; off >>= 1) sum += __shfl_xor(sum, off, 64);
    __shared__ float reds[4];
    if (lane == 0) reds[wid] = sum;
    __syncthreads();
    float tot = reds[0] + reds[1] + reds[2] + reds[3];

    #pragma unroll
    for (int i = 0; i < 16; ++i) p[tid + 256 * i] = vals[i] / tot;
}

// Pass 3: output[b,d] = sum_s w[b,s] * V[b,s,d]. The 1 GiB streaming pass.
// grid: (s-chunk 16, d-chunk 2, b 32). Block covers 1024 dims via float4/lane.
__global__ __launch_bounds__(256) void out_kernel(
    const float* __restrict__ V, const float* __restrict__ w, float* __restrict__ out)
{
    int sc = blockIdx.x;   // 0..15 -> 256 s each
    int dc = blockIdx.y;   // 0..1  -> 1024 d each
    int b  = blockIdx.z;   // 0..31
    int d0 = dc * 1024 + threadIdx.x * 4;
    int s0 = sc * 256;

    __shared__ float wsh[256];
    wsh[threadIdx.x] = w[b * NS + s0 + threadIdx.x];
    __syncthreads();

    const float* vp = V + ((size_t)(b * NS + s0)) * ND + d0;
    float4 acc = make_float4(0.f, 0.f, 0.f, 0.f);
    #pragma unroll 4
    for (int i = 0; i < 256; ++i) {
        float4 v = *(const float4*)(vp + (size_t)i * ND);
        float c = wsh[i];          // uniform -> LDS broadcast, no conflict
        acc.x += c * v.x; acc.y += c * v.y; acc.z += c * v.z; acc.w += c * v.w;
    }
    float* o = out + b * ND + d0;
    atomicAdd(o + 0, acc.x);
    atomicAdd(o + 1, acc.y);
    atomicAdd(o + 2, acc.z);
    atomicAdd(o + 3, acc.w);
}

extern "C" void kernel_launch(void* const* d_in, const int* in_sizes, int n_in,
                              void* d_out, int out_size, void* d_ws, size_t ws_size,
                              hipStream_t stream) {
    (void)in_sizes; (void)n_in; (void)d_ws; (void)ws_size; (void)out_size;
    const float* x  = (const float*)d_in[0];
    const float* V  = (const float*)d_in[1];   // cached_states
    const float* t  = (const float*)d_in[2];
    const float* wq = (const float*)d_in[3];
    const float* bq = (const float*)d_in[4];
    const float* wk = (const float*)d_in[5];
    const float* bk = (const float*)d_in[6];

    float* out     = (float*)d_out;            // (32, 2048)
    float* weights = out + NB * ND;            // (32, 4096) — also staging for raw scores

    // zero the atomic accumulation target (d_out is poisoned 0xAA each call)
    hipMemsetAsync(out, 0, (size_t)NB * ND * sizeof(float), stream);

    // 131072 rows / 8 rows-per-wave / 4 waves-per-block = 4096 blocks
    scores_kernel<<<dim3(4096), dim3(256), 0, stream>>>(x, V, t, wq, bq, wk, bk, weights);
    softmax_kernel<<<dim3(NB), dim3(256), 0, stream>>>(weights);
    out_kernel<<<dim3(16, 2, NB), dim3(256), 0, stream>>>(V, weights, out);
}

// Round 2
// 1347.491 us; speedup vs baseline: 1.0060x; 1.0060x over previous
//
#include <hip/hip_runtime.h>
#include <math.h>

#define NB  32
#define NS  4096
#define ND  2048
#define NDH 128
#define LUTN 4096

typedef float fvec4 __attribute__((ext_vector_type(4)));

// Reference LUT semantics:
//   idx = mod(floor(theta * (4096 / 2pi)), 4096)          (floor-mod, f32 mult)
//   sin_tab[idx] = sin(idx * (2pi/4096))  (angle formed by f32 mult)
// Reproduce the quantization exactly, then evaluate sin/cos of the quantized
// angle directly (== table entry up to ~1 ulp of sincosf).
static __device__ __forceinline__ void lut_sincos(float theta, float* s, float* c) {
    const float IDX_SCALE = (float)(4096.0 / (2.0 * 3.14159265358979323846));
    const float ANG_STEP  = (float)((2.0 * 3.14159265358979323846) / 4096.0);
    float f = floorf(theta * IDX_SCALE);
    int idx = ((int)f) & (LUTN - 1);   // & == floor-mod for pow2 on two's complement
    float ang = (float)idx * ANG_STEP;
    sincosf(ang, s, c);
}

// Pass 1: raw scores. One wave per 16 consecutive key rows (same b).
// lane holds dims d0 = 2*lane, 2*lane+1 of the 128-dim head.
__global__ __launch_bounds__(256) void scores_kernel(
    const float* __restrict__ x, const float* __restrict__ V,
    const float* __restrict__ t, const float* __restrict__ wq,
    const float* __restrict__ bq, const float* __restrict__ wk,
    const float* __restrict__ bk, float* __restrict__ scores)
{
    const int ROWS = 16;
    int lane  = threadIdx.x & 63;
    int gwave = blockIdx.x * 4 + (threadIdx.x >> 6);
    int row0  = gwave * ROWS;          // global row = b*NS + s
    int b  = row0 >> 12;               // NS = 4096
    int s0 = row0 & (NS - 1);
    int d0 = lane * 2;

    const float PHIF = (float)1.61803398874989484820458683436563811;
    float tphi = t[b] * PHIF;

    // query fragment for this lane's two dims (amortized over 16 rows)
    float qs0, qc0, qs1, qc1;
    {
        float xv0 = x[b * ND + d0];
        float xv1 = x[b * ND + d0 + 1];
        float th0 = (xv0 / (1.0f + fabsf(wq[d0]))     + bq[d0])     + tphi;
        float th1 = (xv1 / (1.0f + fabsf(wq[d0 + 1])) + bq[d0 + 1]) + tphi;
        lut_sincos(th0, &qs0, &qc0);
        lut_sincos(th1, &qs1, &qc1);
    }
    float den0 = 1.0f + fabsf(wk[d0]);
    float den1 = 1.0f + fabsf(wk[d0 + 1]);
    float bk0 = bk[d0], bk1 = bk[d0 + 1];

    const float* vp = V + ((size_t)(b * NS + s0)) * ND + d0;
    #pragma unroll 4
    for (int r = 0; r < ROWS; ++r) {
        float2 kv = *(const float2*)(vp + (size_t)r * ND);
        float th0 = kv.x / den0 + bk0;
        float th1 = kv.y / den1 + bk1;
        float ks0, kc0, ks1, kc1;
        lut_sincos(th0, &ks0, &kc0);
        lut_sincos(th1, &ks1, &kc1);
        float acc = qc0 * kc0 + qs0 * ks0 + qc1 * kc1 + qs1 * ks1;
        #pragma unroll
        for (int off = 32; off > 0; off >>= 1)
            acc += __shfl_xor(acc, off, 64);
        if (lane == 0)
            scores[b * NS + s0 + r] = acc * 0.0625f;   // /16 == *2^-4, exact
    }
}

// Pass 2: in-place softmax over S per batch row. One block per b.
__global__ __launch_bounds__(256) void softmax_kernel(float* __restrict__ sw) {
    int b = blockIdx.x;
    float* p = sw + b * NS;
    int tid  = threadIdx.x;
    int lane = tid & 63, wid = tid >> 6;

    float vals[16];
    float m = -INFINITY;
    #pragma unroll
    for (int i = 0; i < 16; ++i) { vals[i] = p[tid + 256 * i]; m = fmaxf(m, vals[i]); }
    #pragma unroll
    for (int off = 32; off > 0; off >>= 1) m = fmaxf(m, __shfl_xor(m, off, 64));
    __shared__ float redm[4];
    if (lane == 0) redm[wid] = m;
    __syncthreads();
    m = fmaxf(fmaxf(redm[0], redm[1]), fmaxf(redm[2], redm[3]));

    float sum = 0.f;
    #pragma unroll
    for (int i = 0; i < 16; ++i) { vals[i] = expf(vals[i] - m); sum += vals[i]; }
    #pragma unroll
    for (int off = 32; off > 0; off >>= 1) sum += __shfl_xor(sum, off, 64);
    __shared__ float reds[4];
    if (lane == 0) reds[wid] = sum;
    __syncthreads();
    float tot = reds[0] + reds[1] + reds[2] + reds[3];

    #pragma unroll
    for (int i = 0; i < 16; ++i) p[tid + 256 * i] = vals[i] / tot;
}

// Pass 3: output[b,d] = sum_s w[b,s] * V[b,s,d]. The 1 GiB streaming pass.
// grid: (s-chunk 32, b 32). Each block covers a FULL 2048-dim row (8 KB
// contiguous per iteration) x 128 rows. 2 independent float4 loads per
// thread per iter, unroll 4 -> 8 outstanding loads/thread.
__global__ __launch_bounds__(256) void out_kernel(
    const float* __restrict__ V, const float* __restrict__ w, float* __restrict__ out)
{
    int sc = blockIdx.x;   // 0..31 -> 128 s each
    int b  = blockIdx.y;   // 0..31
    int s0 = sc * 128;
    int tid = threadIdx.x;

    __shared__ float wsh[128];
    if (tid < 128) wsh[tid] = w[b * NS + s0 + tid];
    __syncthreads();

    const float* vp = V + ((size_t)(b * NS + s0)) * ND;
    int d0 = tid * 4;      // first half of row; second half at +1024
    fvec4 a0 = (fvec4)0.f, a1 = (fvec4)0.f;
    #pragma unroll 4
    for (int i = 0; i < 128; ++i) {
        const float* row = vp + (size_t)i * ND;
        fvec4 v0 = __builtin_nontemporal_load((const fvec4*)(row + d0));
        fvec4 v1 = __builtin_nontemporal_load((const fvec4*)(row + d0 + 1024));
        float c = wsh[i];          // uniform -> LDS broadcast, no conflict
        a0 += c * v0;
        a1 += c * v1;
    }
    float* o = out + b * ND + d0;
    atomicAdd(o + 0, a0.x);
    atomicAdd(o + 1, a0.y);
    atomicAdd(o + 2, a0.z);
    atomicAdd(o + 3, a0.w);
    atomicAdd(o + 1024 + 0, a1.x);
    atomicAdd(o + 1024 + 1, a1.y);
    atomicAdd(o + 1024 + 2, a1.z);
    atomicAdd(o + 1024 + 3, a1.w);
}

extern "C" void kernel_launch(void* const* d_in, const int* in_sizes, int n_in,
                              void* d_out, int out_size, void* d_ws, size_t ws_size,
                              hipStream_t stream) {
    (void)in_sizes; (void)n_in; (void)d_ws; (void)ws_size; (void)out_size;
    const float* x  = (const float*)d_in[0];
    const float* V  = (const float*)d_in[1];   // cached_states
    const float* t  = (const float*)d_in[2];
    const float* wq = (const float*)d_in[3];
    const float* bq = (const float*)d_in[4];
    const float* wk = (const float*)d_in[5];
    const float* bk = (const float*)d_in[6];

    float* out     = (float*)d_out;            // (32, 2048)
    float* weights = out + NB * ND;            // (32, 4096) — also staging for raw scores

    // zero the atomic accumulation target (d_out is poisoned 0xAA each call)
    hipMemsetAsync(out, 0, (size_t)NB * ND * sizeof(float), stream);

    // 131072 rows / 16 rows-per-wave / 4 waves-per-block = 2048 blocks
    scores_kernel<<<dim3(2048), dim3(256), 0, stream>>>(x, V, t, wq, bq, wk, bk, weights);
    softmax_kernel<<<dim3(NB), dim3(256), 0, stream>>>(weights);
    out_kernel<<<dim3(32, NB), dim3(256), 0, stream>>>(V, weights, out);
}